// Round 1
// 110.115 us; speedup vs baseline: 1.0128x; 1.0128x over previous
//
#include <hip/hip_runtime.h>

typedef __bf16 bf16_t;
typedef __bf16 bf16x8 __attribute__((ext_vector_type(8)));
typedef __bf16 bf16x4 __attribute__((ext_vector_type(4)));
typedef float f32x4 __attribute__((ext_vector_type(4)));

__device__ __forceinline__ void async16(const void* g, void* l) {
  __builtin_amdgcn_global_load_lds(
      (const __attribute__((address_space(1))) unsigned int*)g,
      (__attribute__((address_space(3))) unsigned int*)l,
      16, 0, 0);
}

// ---------------------------------------------------------------------------
// Fused prep for Bcat (512 x 1024 bf16):
//   blocks 0..255   : convert proj_R (256x1024 f32) -> Bcat rows 256..511
//   blocks 256..511 : LDS-tiled transpose proj_L (1024x256 f32) -> rows 0..255
// ---------------------------------------------------------------------------
__global__ void prep_Bcat(const float* __restrict__ projL,
                          const float* __restrict__ projR,
                          bf16_t* __restrict__ Bcat) {
  const int t = threadIdx.x;
  if (blockIdx.x < 256) {
    int i = blockIdx.x * 256 + t;
    float4 v = ((const float4*)projR)[i];
    bf16x4 o;
    o[0] = (bf16_t)v.x; o[1] = (bf16_t)v.y; o[2] = (bf16_t)v.z; o[3] = (bf16_t)v.w;
    ((bf16x4*)(Bcat + (long)256 * 1024))[i] = o;
  } else {
    __shared__ float tile[32][33];
    const int bb = blockIdx.x - 256;
    const int n0 = (bb & 7) * 32;   // col block in projL (N=256)
    const int k0 = (bb >> 3) * 32;  // row block in projL (K=1024)
    const int tx = t & 31;
    const int ty = t >> 5;  // 0..7
#pragma unroll
    for (int i = 0; i < 32; i += 8)
      tile[ty + i][tx] = projL[(long)(k0 + ty + i) * 256 + n0 + tx];
    __syncthreads();
#pragma unroll
    for (int i = 0; i < 32; i += 8)
      Bcat[(long)(n0 + ty + i) * 1024 + k0 + tx] = (bf16_t)tile[tx][ty + i];
  }
}

// ---------------------------------------------------------------------------
// GEMM1 (fused fp32->bf16 on A):
//   LR(8192x512 bf16) = batch(8192x1024 f32) @ Bcat(512x1024 bf16)^T
// 64x128 tile, 512 blocks -> 2 blocks/CU. 256 thr (4 waves, 2Mx2N).
// T14 register-prefetch on A: the 8 dwordx4 loads for step s+1 are issued
// AFTER barrier #1 of step s, so their HBM/L2 latency hides under the 4xkc
// MFMA block instead of being serially drained by the pre-cvt s_waitcnt.
// B async16 issued at step top (Bs free after prev barrier #2); its ~L2
// latency overlaps the cvt+ds_write of A.
// XCD swizzle: tm = bx&127, tn = bx>>7 -> the 4 blocks sharing an A row-tile
// are 128 apart (128 % 8 == 0 -> same XCD) -> A re-reads hit local L2.
// ---------------------------------------------------------------------------
__global__ __launch_bounds__(256, 2) void gemm1_fusedA(
    const float* __restrict__ batch, const bf16_t* __restrict__ Bcat,
    bf16_t* __restrict__ LR) {
  const int bx = blockIdx.x;
  const int tm = (bx & 127) * 64;  // M tile (8192/64 = 128)
  const int tn = (bx >> 7) * 128;  // N tile (512/128 = 4)

  __shared__ __attribute__((aligned(16))) bf16_t As[4 * 2048];  // 64 x 128
  __shared__ __attribute__((aligned(16))) bf16_t Bs[4 * 4096];  // 128 x 128

  const int t = threadIdx.x;
  const int lane = t & 63;
  const int quad = lane >> 4;
  const int l15 = lane & 15;
  const int wave = t >> 6;
  const int wr = (wave >> 1) * 32;  // 0 / 32  (M)
  const int wc = (wave & 1) * 64;   // 0 / 64  (N)

  // B staging (async16, m97 map): per 128x32 sub-tile row t>>2, cols (t&3)*8
  const int rS = t >> 2;
  const int cS = (t & 3) * 8;
  const bf16_t* gB = Bcat + (long)(tn + rS) * 1024 + cS;
  bf16_t* lB = Bs + t * 8;

  // A fp32 source: thread t -> rows (t>>4)+16i (i=0..3), k-chunk (t&15)*8
  const int rA = t >> 4;        // 0..15
  const int cA = (t & 15) * 8;  // 0,8,..,120
  const float* gA = batch + (long)(tm + rA) * 1024 + cA;
  // LDS dest: sub-tile cA>>5 (2048 elem each), col cA&31, row added per i
  bf16_t* lA = As + (cA >> 5) * 2048 + (cA & 31);

  f32x4 acc[2][4];
#pragma unroll
  for (int i = 0; i < 2; ++i)
#pragma unroll
    for (int j = 0; j < 4; ++j)
      acc[i][j] = (f32x4){0.f, 0.f, 0.f, 0.f};

  // Prologue: issue A loads for step 0 (in regs across the loop head).
  float4 fa[4], fb[4];
#pragma unroll
  for (int i = 0; i < 4; ++i) {
    const float* p = gA + (long)16 * i * 1024;
    fa[i] = *(const float4*)p;
    fb[i] = *(const float4*)(p + 4);
  }

  for (int s = 0; s < 8; ++s) {  // K=1024, BK=128
    const int k0 = s * 128;
    // B async16 first: its latency overlaps the A cvt+ds_write below.
#pragma unroll
    for (int kc = 0; kc < 4; ++kc) {
      async16(gB + k0 + kc * 32, lB + kc * 4096);
      async16(gB + k0 + kc * 32 + (long)64 * 1024, lB + kc * 4096 + 2048);
    }
    // cvt + 4 ds_write_b128. fa/fb were issued one step ago and were already
    // drained by the previous __syncthreads -> no serial wait here.
#pragma unroll
    for (int i = 0; i < 4; ++i) {
      bf16x8 v;
      v[0] = (bf16_t)fa[i].x; v[1] = (bf16_t)fa[i].y;
      v[2] = (bf16_t)fa[i].z; v[3] = (bf16_t)fa[i].w;
      v[4] = (bf16_t)fb[i].x; v[5] = (bf16_t)fb[i].y;
      v[6] = (bf16_t)fb[i].z; v[7] = (bf16_t)fb[i].w;
      *(bf16x8*)(lA + (rA + 16 * i) * 32) = v;
    }
    __syncthreads();  // drains async16 B (vmcnt) + ds_writes (lgkm)

    // T14: issue A loads for step s+1 now; they fly under the MFMA block
    // and are (mostly) complete by the time barrier #2's vmcnt(0) drains.
    if (s < 7) {
#pragma unroll
      for (int i = 0; i < 4; ++i) {
        const float* p = gA + (s + 1) * 128 + (long)16 * i * 1024;
        fa[i] = *(const float4*)p;
        fb[i] = *(const float4*)(p + 4);
      }
    }

#pragma unroll
    for (int kc = 0; kc < 4; ++kc) {
      const bf16_t* Ak = As + kc * 2048;
      const bf16_t* Bk = Bs + kc * 4096;
      bf16x8 af[2], bv[4];
#pragma unroll
      for (int i = 0; i < 2; ++i)
        af[i] = *(const bf16x8*)(Ak + (wr + i * 16 + l15) * 32 + quad * 8);
#pragma unroll
      for (int j = 0; j < 4; ++j)
        bv[j] = *(const bf16x8*)(Bk + (wc + j * 16 + l15) * 32 + quad * 8);
#pragma unroll
      for (int i = 0; i < 2; ++i)
#pragma unroll
        for (int j = 0; j < 4; ++j)
          acc[i][j] = __builtin_amdgcn_mfma_f32_16x16x32_bf16(af[i], bv[j],
                                                              acc[i][j], 0, 0, 0);
    }
    __syncthreads();
  }

  // Epilogue -> LR bf16 (ldc=512). C/D: col = lane&15, row = quad*4 + reg
#pragma unroll
  for (int i = 0; i < 2; ++i) {
    const int r0 = tm + wr + i * 16 + quad * 4;
#pragma unroll
    for (int j = 0; j < 4; ++j) {
      const int c0 = tn + wc + j * 16 + l15;
#pragma unroll
      for (int r = 0; r < 4; ++r)
        LR[(long)(r0 + r) * 512 + c0] = (bf16_t)acc[i][j][r];
    }
  }
}

// ---------------------------------------------------------------------------
// GEMM2: out[b](1024x1024 f32) = left[b](1024x256) @ right[b](1024x256)^T + bias
// left = LR[b] cols 0..255, right = LR[b] cols 256..511 (ld=512, bf16).
// 128x128 tile; K=256 as BK=64 x 4 steps, DOUBLE-BUFFERED T3-min schedule:
//   STAGE(buf^1, s+1)  ->  COMPUTE(buf, s)  ->  one __syncthreads per step
// so the async16 latency for step s+1 hides under step s's 32 MFMA (plus the
// co-resident block), instead of a serial stage->drain->compute per step.
// LDS = 2 x (16 KB A + 16 KB B) = 64 KB -> still 2 blocks/CU.
// Flat 512-block grid, BATCH-to-XCD pinning: b = bx&7, tile = bx>>3 -> each
// batch's 1 MB LR slice is fetched once into one XCD's L2 and re-read there.
// ---------------------------------------------------------------------------
__global__ __launch_bounds__(256, 2) void gemm2(const bf16_t* __restrict__ LR,
                                                float* __restrict__ out,
                                                const float* __restrict__ bias) {
  const int bx = blockIdx.x;
  const int bz = bx & 7;         // batch -> XCD
  const int tile = bx >> 3;      // 0..63
  const int tm = (tile & 7) * 128;   // row tile (i)
  const int tn = (tile >> 3) * 128;  // col tile (j)
  const bf16_t* LRb = LR + (long)bz * 1024 * 512;

  // [buf][kc][128 rows][32 cols] bf16 ; buf stride 8192, kc stride 4096
  __shared__ __attribute__((aligned(16))) bf16_t As[2 * 8192];
  __shared__ __attribute__((aligned(16))) bf16_t Bs[2 * 8192];

  const int t = threadIdx.x;
  const int lane = t & 63;
  const int quad = lane >> 4;
  const int l15 = lane & 15;
  const int wave = t >> 6;
  const int wr = (wave >> 1) * 64;
  const int wc = (wave & 1) * 64;

  const int rS = t >> 2;          // 0..63
  const int cS = (t & 3) * 8;     // 0,8,16,24
  const bf16_t* gA = LRb + (long)(tm + rS) * 512 + cS;        // left
  const bf16_t* gB = LRb + (long)(tn + rS) * 512 + 256 + cS;  // right

  f32x4 acc[4][4];
#pragma unroll
  for (int i = 0; i < 4; ++i)
#pragma unroll
    for (int j = 0; j < 4; ++j)
      acc[i][j] = (f32x4){0.f, 0.f, 0.f, 0.f};

  // stage BK=64 slice s into buffer buf: 8 async16/thread (A:4, B:4)
  auto STAGE = [&](int buf, int s) {
    const int k0 = s * 64;
    bf16_t* dA = As + buf * 8192 + t * 8;  // t*8 == (t>>2)*32 + (t&3)*8
    bf16_t* dB = Bs + buf * 8192 + t * 8;
#pragma unroll
    for (int kc = 0; kc < 2; ++kc) {
      const int ko = k0 + kc * 32;
      async16(gA + ko, dA + kc * 4096);
      async16(gA + ko + (long)64 * 512, dA + kc * 4096 + 2048);
      async16(gB + ko, dB + kc * 4096);
      async16(gB + ko + (long)64 * 512, dB + kc * 4096 + 2048);
    }
  };

  STAGE(0, 0);
  __syncthreads();  // drains prologue async16

#pragma unroll
  for (int s = 0; s < 4; ++s) {  // K=256, BK=64
    if (s < 3) STAGE((s + 1) & 1, s + 1);  // prefetch into other buffer
    const bf16_t* Ab = As + (s & 1) * 8192;
    const bf16_t* Bb = Bs + (s & 1) * 8192;
#pragma unroll
    for (int kc = 0; kc < 2; ++kc) {
      const bf16_t* Ak = Ab + kc * 4096;
      const bf16_t* Bk = Bb + kc * 4096;
      bf16x8 af[4], bv[4];
#pragma unroll
      for (int i = 0; i < 4; ++i)
        af[i] = *(const bf16x8*)(Ak + (wr + i * 16 + l15) * 32 + quad * 8);
#pragma unroll
      for (int j = 0; j < 4; ++j)
        bv[j] = *(const bf16x8*)(Bk + (wc + j * 16 + l15) * 32 + quad * 8);
#pragma unroll
      for (int i = 0; i < 4; ++i)
#pragma unroll
        for (int j = 0; j < 4; ++j)
          acc[i][j] = __builtin_amdgcn_mfma_f32_16x16x32_bf16(af[i], bv[j],
                                                              acc[i][j], 0, 0, 0);
    }
    if (s < 3) __syncthreads();  // drains prefetch; protects buf reuse
  }

  float* C = out + (long)bz * 1024 * 1024;
  const float bvadd = bias[0];
#pragma unroll
  for (int i = 0; i < 4; ++i) {
    const int r0 = tm + wr + i * 16 + quad * 4;
#pragma unroll
    for (int j = 0; j < 4; ++j) {
      const int c0 = tn + wc + j * 16 + l15;
#pragma unroll
      for (int r = 0; r < 4; ++r)
        C[(long)(r0 + r) * 1024 + c0] = acc[i][j][r] + bvadd;
    }
  }
}

extern "C" void kernel_launch(void* const* d_in, const int* in_sizes, int n_in,
                              void* d_out, int out_size, void* d_ws,
                              size_t ws_size, hipStream_t stream) {
  const float* batch = (const float*)d_in[0];  // (8,1024,1024)
  const float* projL = (const float*)d_in[1];  // (1024,256)
  const float* projR = (const float*)d_in[2];  // (256,1024)
  const float* bias = (const float*)d_in[3];   // (1,)
  float* out = (float*)d_out;                  // (8,1024,1024)

  // workspace: Bcat (512x1024 bf16 = 1 MB) then LR (8192x512 bf16 = 8.4 MB)
  char* ws = (char*)d_ws;
  bf16_t* Bcat = (bf16_t*)ws;
  bf16_t* LR = (bf16_t*)(ws + (long)512 * 1024 * 2);

  // 1) Bcat: rows 0..255 = proj_L^T, rows 256..511 = proj_R (both bf16)
  prep_Bcat<<<512, 256, 0, stream>>>(projL, projR, Bcat);

  // 2) GEMM1: LR = batch @ Bcat^T (fp32 A converted in-flight; T14 A-prefetch)
  gemm1_fusedA<<<512, 256, 0, stream>>>(batch, Bcat, LR);

  // 3) GEMM2: out[b] = left[b] @ right[b]^T + bias (dbuf T3-min, XCD pinning)
  gemm2<<<512, 256, 0, stream>>>(LR, out, bias);
}